// Round 11
// baseline (100.197 us; speedup 1.0000x reference)
//
#include <hip/hip_runtime.h>
#include <math.h>

namespace {

constexpr int Bn   = 32;
constexpr int Kn   = 32;
constexpr int Fn   = 2048;
constexpr int HIDn = 2;
constexpr int NCLSn = 47;
constexpr float EPSn = 1e-5f;
constexpr int NT = 256;     // threads per block
constexpr int GS = 32;      // split factor along the reduced dim
constexpr int FT = Fn / GS; // 64: LDS tile = one slice
// RF = 8 outputs per thread: NT*8 = 2048 = Fn covered by one block in x.

typedef float v2f __attribute__((ext_vector_type(2)));
typedef float v4f __attribute__((ext_vector_type(4)));

__device__ inline float wave_sum(float v) {
    #pragma unroll
    for (int off = 32; off > 0; off >>= 1) v += __shfl_down(v, off, 64);
    return v;
}

// ---------------------------------------------------------------------------
// K1: ysum[b,g] = sum_k neighbor[b,k,0,g] (float4); block 0 zeroes BN stats.
__global__ void ysum_kernel(const float* __restrict__ neighbor,
                            float* __restrict__ ysum,
                            double* __restrict__ stats) {
    int idx4 = blockIdx.x * NT + threadIdx.x;         // over B*F/4 quads
    if (blockIdx.x == 0 && threadIdx.x < 8) stats[threadIdx.x] = 0.0;
    int b = idx4 >> 9;                                // 512 quads per b
    int gq = idx4 & 511;
    const float* p = neighbor + (size_t)b * Kn * Fn + gq * 4;
    v4f s = (v4f){0.f, 0.f, 0.f, 0.f};
    #pragma unroll
    for (int k = 0; k < Kn; ++k) s += *(const v4f*)(p + (size_t)k * Fn);
    *(v4f*)(ysum + (size_t)b * Fn + gq * 4) = s;
}

// ---------------------------------------------------------------------------
// K2: partial denom: dpart[fs][b][g] = sum_{f in slice fs} sqrt(|x_f*y_g + x_g*y_f|)
// grid (GS, Bn) = (32, 32); each thread owns 8 adjacent g (RF=8).
__global__ __launch_bounds__(NT, 4)
void denom_partial_kernel(const float* __restrict__ x, const float* __restrict__ ysum,
                          float* __restrict__ dpart) {
    __shared__ v4f xyf4[FT];                          // (x,x,y,y) per f
    const int fs  = blockIdx.x;
    const int b   = blockIdx.y;
    const int tid = threadIdx.x;
    const float* xb = x + (size_t)b * Fn;
    const float* yb = ysum + (size_t)b * Fn;
    if (tid < FT) {
        int f = fs * FT + tid;
        float xv = xb[f], yv = yb[f];
        xyf4[tid] = (v4f){xv, xv, yv, yv};
    }
    const int gbase = tid * 8;                        // adjacent octet
    const v4f Xa = *(const v4f*)(xb + gbase);
    const v4f Xb = *(const v4f*)(xb + gbase + 4);
    const v4f Ya = *(const v4f*)(yb + gbase);
    const v4f Yb = *(const v4f*)(yb + gbase + 4);
    v2f Xg[4] = {(v2f){Xa.x, Xa.y}, (v2f){Xa.z, Xa.w}, (v2f){Xb.x, Xb.y}, (v2f){Xb.z, Xb.w}};
    v2f Yg[4] = {(v2f){Ya.x, Ya.y}, (v2f){Ya.z, Ya.w}, (v2f){Yb.x, Yb.y}, (v2f){Yb.z, Yb.w}};
    __syncthreads();
    v2f d[4] = {(v2f){0.f, 0.f}, (v2f){0.f, 0.f}, (v2f){0.f, 0.f}, (v2f){0.f, 0.f}};
    #pragma unroll 8
    for (int j = 0; j < FT; ++j) {
        v4f q = xyf4[j];
        v2f xf = (v2f){q.x, q.y}, yf = (v2f){q.z, q.w};
        #pragma unroll
        for (int p = 0; p < 4; ++p) {
            v2f v = Xg[p] * yf + Yg[p] * xf;
            d[p].x += __builtin_amdgcn_sqrtf(fabsf(v.x));
            d[p].y += __builtin_amdgcn_sqrtf(fabsf(v.y));
        }
    }
    size_t base = ((size_t)fs * Bn + b) * Fn + gbase;
    *(v4f*)(dpart + base)     = (v4f){d[0].x, d[0].y, d[1].x, d[1].y};
    *(v4f*)(dpart + base + 4) = (v4f){d[2].x, d[2].y, d[3].x, d[3].y};
}

// ---------------------------------------------------------------------------
// Packed inner loop: thread owns 8 adjacent f (4 pairs), both channels.
__device__ inline void mv_loop8(const v4f* __restrict__ xy4, const v4f* __restrict__ tt4,
                                const v2f Xf[4], const v2f Yf[4],
                                v2f a0[4], v2f a1[4]) {
    #pragma unroll 8
    for (int j = 0; j < FT; ++j) {
        v4f q = xy4[j];
        v2f xg = (v2f){q.x, q.y}, yg = (v2f){q.z, q.w};
        v4f u = tt4[j];
        v2f t0 = (v2f){u.x, u.y}, t1 = (v2f){u.z, u.w};
        #pragma unroll
        for (int p = 0; p < 4; ++p) {
            v2f v = Xf[p] * yg + Yf[p] * xg;          // s(f-pair p, g_j)
            v2f S;
            S.x = copysignf(__builtin_amdgcn_sqrtf(fabsf(v.x)), v.x);
            S.y = copysignf(__builtin_amdgcn_sqrtf(fabsf(v.y)), v.y);
            a0[p] += S * t0;
            a1[p] += S * t1;
        }
    }
}

// ---------------------------------------------------------------------------
// K3: pass-1 partial matvec. grid (GS, Bn); thread owns 8 adjacent f.
// Prologue: distributed dpart reduce (4 groups x 64 threads x 8 slices),
// computes rden (stored for mv2) and t1 = (w1*x+b1)*rden.
__global__ __launch_bounds__(NT, 4)
void mv1_partial_kernel(const float* __restrict__ x, const float* __restrict__ ysum,
                        const float* __restrict__ dpart,
                        const float* __restrict__ w1, const float* __restrict__ b1,
                        float* __restrict__ rden, float* __restrict__ part) {
    __shared__ v4f xy4[FT], tt4[FT];
    __shared__ float redp[4][FT];
    const int gs  = blockIdx.x;
    const int b   = blockIdx.y;
    const int tid = threadIdx.x;
    const float* xb = x + (size_t)b * Fn;
    const float* yb = ysum + (size_t)b * Fn;
    {
        int grp = tid >> 6, gi = tid & 63;
        int g = gs * FT + gi;
        float p = 0.f;
        #pragma unroll
        for (int k = 0; k < GS / 4; ++k) {
            int fs = grp * (GS / 4) + k;
            p += dpart[((size_t)fs * Bn + b) * Fn + g];
        }
        redp[grp][gi] = p;
    }
    __syncthreads();
    if (tid < FT) {
        int g = gs * FT + tid;
        float d = (redp[0][tid] + redp[1][tid]) + (redp[2][tid] + redp[3][tid]);
        float r = 1.0f / (d + 1e-7f);
        rden[(size_t)b * Fn + g] = r;
        float xg = xb[g], yg = yb[g];
        float t0 = fmaf(w1[0], xg, b1[0]) * r;
        float t1 = fmaf(w1[1], xg, b1[1]) * r;
        xy4[tid] = (v4f){xg, xg, yg, yg};
        tt4[tid] = (v4f){t0, t0, t1, t1};
    }
    const int fbase = tid * 8;
    const v4f Xa = *(const v4f*)(xb + fbase);
    const v4f Xb = *(const v4f*)(xb + fbase + 4);
    const v4f Ya = *(const v4f*)(yb + fbase);
    const v4f Yb = *(const v4f*)(yb + fbase + 4);
    v2f Xf[4] = {(v2f){Xa.x, Xa.y}, (v2f){Xa.z, Xa.w}, (v2f){Xb.x, Xb.y}, (v2f){Xb.z, Xb.w}};
    v2f Yf[4] = {(v2f){Ya.x, Ya.y}, (v2f){Ya.z, Ya.w}, (v2f){Yb.x, Yb.y}, (v2f){Yb.z, Yb.w}};
    __syncthreads();
    v2f a0[4] = {(v2f){0.f, 0.f}, (v2f){0.f, 0.f}, (v2f){0.f, 0.f}, (v2f){0.f, 0.f}};
    v2f a1[4] = {(v2f){0.f, 0.f}, (v2f){0.f, 0.f}, (v2f){0.f, 0.f}, (v2f){0.f, 0.f}};
    mv_loop8(xy4, tt4, Xf, Yf, a0, a1);
    size_t base = (((size_t)gs * Bn + b) * HIDn) * Fn;
    *(v4f*)(part + base + fbase)          = (v4f){a0[0].x, a0[0].y, a0[1].x, a0[1].y};
    *(v4f*)(part + base + fbase + 4)      = (v4f){a0[2].x, a0[2].y, a0[3].x, a0[3].y};
    *(v4f*)(part + base + Fn + fbase)     = (v4f){a1[0].x, a1[0].y, a1[1].x, a1[1].y};
    *(v4f*)(part + base + Fn + fbase + 4) = (v4f){a1[2].x, a1[2].y, a1[3].x, a1[3].y};
}

// ---------------------------------------------------------------------------
// K5: pass-2 partial matvec: reads rden (from mv1) + out1 + BN1 stats.
__global__ __launch_bounds__(NT, 4)
void mv2_partial_kernel(const float* __restrict__ x, const float* __restrict__ ysum,
                        const float* __restrict__ rden, const float* __restrict__ out1,
                        const double* __restrict__ stats,
                        const float* __restrict__ g1, const float* __restrict__ beta1,
                        const float* __restrict__ w2, const float* __restrict__ b2,
                        float* __restrict__ part) {
    __shared__ v4f xy4[FT], tt4[FT];
    const int gs  = blockIdx.x;
    const int b   = blockIdx.y;
    const int tid = threadIdx.x;
    const float* xb = x + (size_t)b * Fn;
    const float* yb = ysum + (size_t)b * Fn;
    if (tid < FT) {
        const double N = (double)(Bn * Fn);
        double m0d = stats[0] / N, m1d = stats[1] / N;
        float mean0 = (float)m0d, mean1 = (float)m1d;
        float var0 = (float)(stats[2] / N - m0d * m0d);
        float var1 = (float)(stats[3] / N - m1d * m1d);
        float inv0 = rsqrtf(var0 + EPSn) * g1[0];
        float inv1 = rsqrtf(var1 + EPSn) * g1[1];
        int g = gs * FT + tid;
        float r = rden[(size_t)b * Fn + g];
        size_t obase = ((size_t)b * HIDn) * Fn + g;
        float o0 = out1[obase], o1 = out1[obase + Fn];
        float y0 = fmaf(o0 - mean0, inv0, beta1[0]);
        float y1 = fmaf(o1 - mean1, inv1, beta1[1]);
        float z0 = y0 / (1.f + fabsf(y0));
        float z1 = y1 / (1.f + fabsf(y1));
        float t0 = fmaf(w2[0], z0, fmaf(w2[1], z1, b2[0])) * r;
        float t1 = fmaf(w2[2], z0, fmaf(w2[3], z1, b2[1])) * r;
        float xg = xb[g], yg = yb[g];
        xy4[tid] = (v4f){xg, xg, yg, yg};
        tt4[tid] = (v4f){t0, t0, t1, t1};
    }
    const int fbase = tid * 8;
    const v4f Xa = *(const v4f*)(xb + fbase);
    const v4f Xb = *(const v4f*)(xb + fbase + 4);
    const v4f Ya = *(const v4f*)(yb + fbase);
    const v4f Yb = *(const v4f*)(yb + fbase + 4);
    v2f Xf[4] = {(v2f){Xa.x, Xa.y}, (v2f){Xa.z, Xa.w}, (v2f){Xb.x, Xb.y}, (v2f){Xb.z, Xb.w}};
    v2f Yf[4] = {(v2f){Ya.x, Ya.y}, (v2f){Ya.z, Ya.w}, (v2f){Yb.x, Yb.y}, (v2f){Yb.z, Yb.w}};
    __syncthreads();
    v2f a0[4] = {(v2f){0.f, 0.f}, (v2f){0.f, 0.f}, (v2f){0.f, 0.f}, (v2f){0.f, 0.f}};
    v2f a1[4] = {(v2f){0.f, 0.f}, (v2f){0.f, 0.f}, (v2f){0.f, 0.f}, (v2f){0.f, 0.f}};
    mv_loop8(xy4, tt4, Xf, Yf, a0, a1);
    size_t base = (((size_t)gs * Bn + b) * HIDn) * Fn;
    *(v4f*)(part + base + fbase)          = (v4f){a0[0].x, a0[0].y, a0[1].x, a0[1].y};
    *(v4f*)(part + base + fbase + 4)      = (v4f){a0[2].x, a0[2].y, a0[3].x, a0[3].y};
    *(v4f*)(part + base + Fn + fbase)     = (v4f){a1[0].x, a1[0].y, a1[1].x, a1[1].y};
    *(v4f*)(part + base + Fn + fbase + 4) = (v4f){a1[2].x, a1[2].y, a1[3].x, a1[3].y};
}

// ---------------------------------------------------------------------------
// K4/K6: reduce matvec partials -> out[b,c,f], plus BN statistics.
__global__ void mv_reduce_kernel(const float* __restrict__ part, float* __restrict__ out,
                                 double* __restrict__ stats) {
    __shared__ float red[4][4];
    int pidx = blockIdx.x * NT + threadIdx.x;         // over B*F/4 quads
    int b = pidx >> 9;                                // 512 quads per b
    int fq = pidx & 511;
    const size_t stride = (size_t)Bn * HIDn * Fn;
    size_t base = ((size_t)b * HIDn) * Fn + fq * 4;
    v4f o0 = (v4f){0.f, 0.f, 0.f, 0.f}, o1 = o0;
    #pragma unroll
    for (int gs = 0; gs < GS; ++gs) {
        o0 += *(const v4f*)(part + (size_t)gs * stride + base);
        o1 += *(const v4f*)(part + (size_t)gs * stride + base + Fn);
    }
    *(v4f*)(out + base)      = o0;
    *(v4f*)(out + base + Fn) = o1;
    float s0 = wave_sum((o0.x + o0.y) + (o0.z + o0.w));
    float s1 = wave_sum((o1.x + o1.y) + (o1.z + o1.w));
    float q0 = wave_sum((o0.x * o0.x + o0.y * o0.y) + (o0.z * o0.z + o0.w * o0.w));
    float q1 = wave_sum((o1.x * o1.x + o1.y * o1.y) + (o1.z * o1.z + o1.w * o1.w));
    int wid = threadIdx.x >> 6, lane = threadIdx.x & 63;
    if (lane == 0) { red[wid][0] = s0; red[wid][1] = s1; red[wid][2] = q0; red[wid][3] = q1; }
    __syncthreads();
    if (threadIdx.x == 0) {
        double S0 = 0, S1 = 0, Q0 = 0, Q1 = 0;
        #pragma unroll
        for (int w = 0; w < 4; ++w) {
            S0 += red[w][0]; S1 += red[w][1]; Q0 += red[w][2]; Q1 += red[w][3];
        }
        atomicAdd(&stats[0], S0);
        atomicAdd(&stats[1], S1);
        atomicAdd(&stats[2], Q0);
        atomicAdd(&stats[3], Q1);
    }
}

// ---------------------------------------------------------------------------
// K7: fused BN2 + softsign (into LDS) + classifier. grid (NCLS, B).
__global__ void classifier_kernel(const float* __restrict__ out2, const double* __restrict__ stats,
                                  const float* __restrict__ g2, const float* __restrict__ beta2,
                                  const float* __restrict__ Wc, const float* __restrict__ bc,
                                  float* __restrict__ out) {
    __shared__ float z[HIDn * Fn];  // 16 KiB
    const int n = blockIdx.x;
    const int b = blockIdx.y;
    const double N = (double)(Bn * Fn);
    double m0d = stats[0] / N, m1d = stats[1] / N;
    float mean0 = (float)m0d, mean1 = (float)m1d;
    float var0 = (float)(stats[2] / N - m0d * m0d);
    float var1 = (float)(stats[3] / N - m1d * m1d);
    float inv0 = rsqrtf(var0 + EPSn) * g2[0];
    float inv1 = rsqrtf(var1 + EPSn) * g2[1];
    float bet0 = beta2[0], bet1 = beta2[1];
    const float* src = out2 + (size_t)b * HIDn * Fn;
    #pragma unroll
    for (int it = 0; it < (HIDn * Fn) / NT; ++it) {
        int i = it * NT + threadIdx.x;
        int c = i >> 11;
        float v = src[i];
        float y = fmaf(v - (c ? mean1 : mean0), (c ? inv1 : inv0), (c ? bet1 : bet0));
        z[i] = y / (1.f + fabsf(y));
    }
    __syncthreads();
    const float4* z4 = (const float4*)z;
    const float4* w4 = (const float4*)(Wc + (size_t)n * (HIDn * Fn));
    float acc = 0.f;
    #pragma unroll
    for (int it = 0; it < (HIDn * Fn) / (4 * NT); ++it) {
        int i = it * NT + threadIdx.x;
        float4 a = z4[i];
        float4 w = w4[i];
        acc = fmaf(a.x, w.x, acc);
        acc = fmaf(a.y, w.y, acc);
        acc = fmaf(a.z, w.z, acc);
        acc = fmaf(a.w, w.w, acc);
    }
    __shared__ float red[4];
    float s = wave_sum(acc);
    int wid = threadIdx.x >> 6, lane = threadIdx.x & 63;
    if (lane == 0) red[wid] = s;
    __syncthreads();
    if (threadIdx.x == 0) {
        float tot = (red[0] + red[1]) + (red[2] + red[3]);
        out[(size_t)b * NCLSn + n] = tot + bc[n];
    }
}

} // namespace

extern "C" void kernel_launch(void* const* d_in, const int* in_sizes, int n_in,
                              void* d_out, int out_size, void* d_ws, size_t ws_size,
                              hipStream_t stream) {
    const float* x        = (const float*)d_in[0];
    const float* neighbor = (const float*)d_in[1];
    const float* w1       = (const float*)d_in[2];
    const float* b1       = (const float*)d_in[3];
    const float* g1       = (const float*)d_in[4];
    const float* beta1    = (const float*)d_in[5];
    const float* w2       = (const float*)d_in[6];
    const float* b2       = (const float*)d_in[7];
    const float* g2       = (const float*)d_in[8];
    const float* beta2    = (const float*)d_in[9];
    const float* Wc       = (const float*)d_in[10];
    const float* bc       = (const float*)d_in[11];
    float* out = (float*)d_out;

    float* ws    = (float*)d_ws;
    float* ysum  = ws;                                  // B*F
    float* rden  = ysum + Bn * Fn;                      // B*F
    float* dpart = rden + Bn * Fn;                      // GS*B*F
    float* part  = dpart + (size_t)GS * Bn * Fn;        // GS*B*HID*F
    float* out1  = part + (size_t)GS * Bn * HIDn * Fn;  // B*HID*F
    float* out2  = out1 + Bn * HIDn * Fn;               // B*HID*F
    double* stats = (double*)(out2 + Bn * HIDn * Fn);   // 8 doubles

    const dim3 grid_split(GS, Bn);                      // (32, 32) = 1024 blocks

    ysum_kernel<<<(Bn * Fn / 4) / NT, NT, 0, stream>>>(neighbor, ysum, stats);
    denom_partial_kernel<<<grid_split, NT, 0, stream>>>(x, ysum, dpart);
    mv1_partial_kernel<<<grid_split, NT, 0, stream>>>(x, ysum, dpart, w1, b1, rden, part);
    mv_reduce_kernel<<<(Bn * Fn / 4) / NT, NT, 0, stream>>>(part, out1, stats);
    mv2_partial_kernel<<<grid_split, NT, 0, stream>>>(x, ysum, rden, out1, stats, g1, beta1, w2, b2, part);
    mv_reduce_kernel<<<(Bn * Fn / 4) / NT, NT, 0, stream>>>(part, out2, stats + 4);
    classifier_kernel<<<dim3(NCLSn, Bn), NT, 0, stream>>>(out2, stats + 4, g2, beta2, Wc, bc, out);
}

// Round 12
// 92.719 us; speedup vs baseline: 1.0807x; 1.0807x over previous
//
#include <hip/hip_runtime.h>
#include <math.h>

namespace {

constexpr int Bn   = 32;
constexpr int Kn   = 32;
constexpr int Fn   = 2048;
constexpr int HIDn = 2;
constexpr int NCLSn = 47;
constexpr float EPSn = 1e-5f;
constexpr int NT = 256;     // threads per block
constexpr int GS = 16;      // split factor along the reduced dim (R8/R10 proven optimum)
constexpr int FT = Fn / GS; // 128: LDS tile = one slice

typedef float v2f __attribute__((ext_vector_type(2)));
typedef float v4f __attribute__((ext_vector_type(4)));

__device__ inline float wave_sum(float v) {
    #pragma unroll
    for (int off = 32; off > 0; off >>= 1) v += __shfl_down(v, off, 64);
    return v;
}

// ---------------------------------------------------------------------------
// K1: ysum[b,g] = sum_k neighbor[b,k,0,g] (float4); block 0 zeroes BN stats.
__global__ void ysum_kernel(const float* __restrict__ neighbor,
                            float* __restrict__ ysum,
                            double* __restrict__ stats) {
    int idx4 = blockIdx.x * NT + threadIdx.x;         // over B*F/4 quads
    if (blockIdx.x == 0 && threadIdx.x < 8) stats[threadIdx.x] = 0.0;
    int b = idx4 >> 9;                                // 512 quads per b
    int gq = idx4 & 511;
    const float* p = neighbor + (size_t)b * Kn * Fn + gq * 4;
    v4f s = (v4f){0.f, 0.f, 0.f, 0.f};
    #pragma unroll
    for (int k = 0; k < Kn; ++k) s += *(const v4f*)(p + (size_t)k * Fn);
    *(v4f*)(ysum + (size_t)b * Fn + gq * 4) = s;
}

// ---------------------------------------------------------------------------
// K2: partial denom: dpart[fs][b][g] = sum_{f in slice fs} sqrt(|x_f*y_g + x_g*y_f|)
// grid (Fn/(NT*4), GS, Bn) = (2, 16, 32); thread owns 4 adjacent g.
// LDS: one v4f per f = (x_f, x_f, y_f, y_f) -> single ds_read_b128 per j.
__global__ __launch_bounds__(NT, 4)
void denom_partial_kernel(const float* __restrict__ x, const float* __restrict__ ysum,
                          float* __restrict__ dpart) {
    __shared__ v4f xyf4[FT];                          // (x,x,y,y) per f
    const int gtile = blockIdx.x;
    const int fs    = blockIdx.y;
    const int b     = blockIdx.z;
    const int tid   = threadIdx.x;
    const float* xb = x + (size_t)b * Fn;
    const float* yb = ysum + (size_t)b * Fn;
    if (tid < FT) {
        int f = fs * FT + tid;
        float xv = xb[f], yv = yb[f];
        xyf4[tid] = (v4f){xv, xv, yv, yv};
    }
    const int gbase = (gtile * NT + tid) * 4;         // adjacent quad
    const v4f Xg4 = *(const v4f*)(xb + gbase);
    const v4f Yg4 = *(const v4f*)(yb + gbase);
    const v2f Xg01 = (v2f){Xg4.x, Xg4.y}, Xg23 = (v2f){Xg4.z, Xg4.w};
    const v2f Yg01 = (v2f){Yg4.x, Yg4.y}, Yg23 = (v2f){Yg4.z, Yg4.w};
    __syncthreads();
    v2f d01 = (v2f){0.f, 0.f}, d23 = (v2f){0.f, 0.f};
    #pragma unroll 8
    for (int j = 0; j < FT; ++j) {
        v4f q = xyf4[j];
        v2f xf = (v2f){q.x, q.y}, yf = (v2f){q.z, q.w};
        v2f vA = Xg01 * yf + Yg01 * xf;
        v2f vB = Xg23 * yf + Yg23 * xf;
        v2f sA, sB;
        sA.x = __builtin_amdgcn_sqrtf(fabsf(vA.x));
        sA.y = __builtin_amdgcn_sqrtf(fabsf(vA.y));
        sB.x = __builtin_amdgcn_sqrtf(fabsf(vB.x));
        sB.y = __builtin_amdgcn_sqrtf(fabsf(vB.y));
        d01 += sA;
        d23 += sB;
    }
    v4f dout = (v4f){d01.x, d01.y, d23.x, d23.y};
    *(v4f*)(dpart + ((size_t)fs * Bn + b) * Fn + gbase) = dout;
}

// ---------------------------------------------------------------------------
// Packed inner loop: thread owns 4 adjacent f, accumulates both channels.
// LDS: xy4 = (xg,xg,yg,yg), tt4 = (t0,t0,t1,t1) -> 2 ds_read_b128 per j.
__device__ inline void mv_loop4(const v4f* __restrict__ xy4, const v4f* __restrict__ tt4,
                                v2f Xf01, v2f Xf23, v2f Yf01, v2f Yf23,
                                v2f& a00, v2f& a10, v2f& a01, v2f& a11) {
    #pragma unroll 8
    for (int j = 0; j < FT; ++j) {
        v4f q = xy4[j];
        v2f xg = (v2f){q.x, q.y}, yg = (v2f){q.z, q.w};
        v2f vA = Xf01 * yg + Yf01 * xg;               // s(f01, g)
        v2f vB = Xf23 * yg + Yf23 * xg;               // s(f23, g)
        v2f SA, SB;
        SA.x = copysignf(__builtin_amdgcn_sqrtf(fabsf(vA.x)), vA.x);
        SA.y = copysignf(__builtin_amdgcn_sqrtf(fabsf(vA.y)), vA.y);
        SB.x = copysignf(__builtin_amdgcn_sqrtf(fabsf(vB.x)), vB.x);
        SB.y = copysignf(__builtin_amdgcn_sqrtf(fabsf(vB.y)), vB.y);
        v4f u = tt4[j];
        v2f t0 = (v2f){u.x, u.y}, t1 = (v2f){u.z, u.w};
        a00 += SA * t0;
        a10 += SA * t1;
        a01 += SB * t0;
        a11 += SB * t1;
    }
}

// K3: pass-1 partial matvec with inline denom-reduce + t1 = (w1*x+b1)*rden.
// grid (2, GS, Bn); each thread owns 4 adjacent f, both channels.
__global__ __launch_bounds__(NT, 4)
void mv1_partial_kernel(const float* __restrict__ x, const float* __restrict__ ysum,
                        const float* __restrict__ dpart,
                        const float* __restrict__ w1, const float* __restrict__ b1,
                        float* __restrict__ part) {
    __shared__ v4f xy4[FT], tt4[FT];
    const int ftile = blockIdx.x;
    const int gs    = blockIdx.y;
    const int b     = blockIdx.z;
    const int tid   = threadIdx.x;
    const float* xb = x + (size_t)b * Fn;
    const float* yb = ysum + (size_t)b * Fn;
    if (tid < FT) {
        int g = gs * FT + tid;
        float d = 0.f;
        #pragma unroll
        for (int fs = 0; fs < GS; ++fs) d += dpart[((size_t)fs * Bn + b) * Fn + g];
        float r = 1.0f / (d + 1e-7f);
        float xg = xb[g], yg = yb[g];
        float t0 = fmaf(w1[0], xg, b1[0]) * r;
        float t1 = fmaf(w1[1], xg, b1[1]) * r;
        xy4[tid] = (v4f){xg, xg, yg, yg};
        tt4[tid] = (v4f){t0, t0, t1, t1};
    }
    const int fbase = (ftile * NT + tid) * 4;
    const v4f X4 = *(const v4f*)(xb + fbase);
    const v4f Y4 = *(const v4f*)(yb + fbase);
    __syncthreads();
    v2f a00 = (v2f){0.f, 0.f}, a10 = a00, a01 = a00, a11 = a00;
    mv_loop4(xy4, tt4,
             (v2f){X4.x, X4.y}, (v2f){X4.z, X4.w},
             (v2f){Y4.x, Y4.y}, (v2f){Y4.z, Y4.w}, a00, a10, a01, a11);
    size_t base = (((size_t)gs * Bn + b) * HIDn) * Fn;
    *(v4f*)(part + base + fbase)      = (v4f){a00.x, a00.y, a01.x, a01.y};
    *(v4f*)(part + base + Fn + fbase) = (v4f){a10.x, a10.y, a11.x, a11.y};
}

// K5: pass-2 partial matvec with inline BN1 + softsign + w2 + rden recompute.
__global__ __launch_bounds__(NT, 4)
void mv2_partial_kernel(const float* __restrict__ x, const float* __restrict__ ysum,
                        const float* __restrict__ dpart, const float* __restrict__ out1,
                        const double* __restrict__ stats,
                        const float* __restrict__ g1, const float* __restrict__ beta1,
                        const float* __restrict__ w2, const float* __restrict__ b2,
                        float* __restrict__ part) {
    __shared__ v4f xy4[FT], tt4[FT];
    const int ftile = blockIdx.x;
    const int gs    = blockIdx.y;
    const int b     = blockIdx.z;
    const int tid   = threadIdx.x;
    const float* xb = x + (size_t)b * Fn;
    const float* yb = ysum + (size_t)b * Fn;
    if (tid < FT) {
        const double N = (double)(Bn * Fn);
        double m0d = stats[0] / N, m1d = stats[1] / N;
        float mean0 = (float)m0d, mean1 = (float)m1d;
        float var0 = (float)(stats[2] / N - m0d * m0d);
        float var1 = (float)(stats[3] / N - m1d * m1d);
        float inv0 = rsqrtf(var0 + EPSn) * g1[0];
        float inv1 = rsqrtf(var1 + EPSn) * g1[1];
        int g = gs * FT + tid;
        float d = 0.f;
        #pragma unroll
        for (int fs = 0; fs < GS; ++fs) d += dpart[((size_t)fs * Bn + b) * Fn + g];
        float r = 1.0f / (d + 1e-7f);
        size_t obase = ((size_t)b * HIDn) * Fn + g;
        float o0 = out1[obase], o1 = out1[obase + Fn];
        float y0 = fmaf(o0 - mean0, inv0, beta1[0]);
        float y1 = fmaf(o1 - mean1, inv1, beta1[1]);
        float z0 = y0 / (1.f + fabsf(y0));
        float z1 = y1 / (1.f + fabsf(y1));
        float t0 = fmaf(w2[0], z0, fmaf(w2[1], z1, b2[0])) * r;
        float t1 = fmaf(w2[2], z0, fmaf(w2[3], z1, b2[1])) * r;
        float xg = xb[g], yg = yb[g];
        xy4[tid] = (v4f){xg, xg, yg, yg};
        tt4[tid] = (v4f){t0, t0, t1, t1};
    }
    const int fbase = (ftile * NT + tid) * 4;
    const v4f X4 = *(const v4f*)(xb + fbase);
    const v4f Y4 = *(const v4f*)(yb + fbase);
    __syncthreads();
    v2f a00 = (v2f){0.f, 0.f}, a10 = a00, a01 = a00, a11 = a00;
    mv_loop4(xy4, tt4,
             (v2f){X4.x, X4.y}, (v2f){X4.z, X4.w},
             (v2f){Y4.x, Y4.y}, (v2f){Y4.z, Y4.w}, a00, a10, a01, a11);
    size_t base = (((size_t)gs * Bn + b) * HIDn) * Fn;
    *(v4f*)(part + base + fbase)      = (v4f){a00.x, a00.y, a01.x, a01.y};
    *(v4f*)(part + base + Fn + fbase) = (v4f){a10.x, a10.y, a11.x, a11.y};
}

// ---------------------------------------------------------------------------
// K4/K6: reduce matvec partials -> out[b,c,f], plus BN statistics.
// grid ((B*F/4)/NT = 64, NT); each thread reduces one adjacent f-quad, both ch.
__global__ void mv_reduce_kernel(const float* __restrict__ part, float* __restrict__ out,
                                 double* __restrict__ stats) {
    __shared__ float red[4][4];
    int pidx = blockIdx.x * NT + threadIdx.x;         // over B*F/4 quads
    int b = pidx >> 9;                                // 512 quads per b
    int fq = pidx & 511;
    const size_t stride = (size_t)Bn * HIDn * Fn;
    size_t base = ((size_t)b * HIDn) * Fn + fq * 4;
    v4f o0 = (v4f){0.f, 0.f, 0.f, 0.f}, o1 = o0;
    #pragma unroll
    for (int gs = 0; gs < GS; ++gs) {
        o0 += *(const v4f*)(part + (size_t)gs * stride + base);
        o1 += *(const v4f*)(part + (size_t)gs * stride + base + Fn);
    }
    *(v4f*)(out + base)      = o0;
    *(v4f*)(out + base + Fn) = o1;
    float s0 = wave_sum((o0.x + o0.y) + (o0.z + o0.w));
    float s1 = wave_sum((o1.x + o1.y) + (o1.z + o1.w));
    float q0 = wave_sum((o0.x * o0.x + o0.y * o0.y) + (o0.z * o0.z + o0.w * o0.w));
    float q1 = wave_sum((o1.x * o1.x + o1.y * o1.y) + (o1.z * o1.z + o1.w * o1.w));
    int wid = threadIdx.x >> 6, lane = threadIdx.x & 63;
    if (lane == 0) { red[wid][0] = s0; red[wid][1] = s1; red[wid][2] = q0; red[wid][3] = q1; }
    __syncthreads();
    if (threadIdx.x == 0) {
        double S0 = 0, S1 = 0, Q0 = 0, Q1 = 0;
        #pragma unroll
        for (int w = 0; w < 4; ++w) {
            S0 += red[w][0]; S1 += red[w][1]; Q0 += red[w][2]; Q1 += red[w][3];
        }
        atomicAdd(&stats[0], S0);
        atomicAdd(&stats[1], S1);
        atomicAdd(&stats[2], Q0);
        atomicAdd(&stats[3], Q1);
    }
}

// ---------------------------------------------------------------------------
// K7: fused BN2 + softsign (into LDS) + classifier. grid (NCLS, B).
__global__ void classifier_kernel(const float* __restrict__ out2, const double* __restrict__ stats,
                                  const float* __restrict__ g2, const float* __restrict__ beta2,
                                  const float* __restrict__ Wc, const float* __restrict__ bc,
                                  float* __restrict__ out) {
    __shared__ float z[HIDn * Fn];  // 16 KiB
    const int n = blockIdx.x;
    const int b = blockIdx.y;
    const double N = (double)(Bn * Fn);
    double m0d = stats[0] / N, m1d = stats[1] / N;
    float mean0 = (float)m0d, mean1 = (float)m1d;
    float var0 = (float)(stats[2] / N - m0d * m0d);
    float var1 = (float)(stats[3] / N - m1d * m1d);
    float inv0 = rsqrtf(var0 + EPSn) * g2[0];
    float inv1 = rsqrtf(var1 + EPSn) * g2[1];
    float bet0 = beta2[0], bet1 = beta2[1];
    const float* src = out2 + (size_t)b * HIDn * Fn;
    #pragma unroll
    for (int it = 0; it < (HIDn * Fn) / NT; ++it) {
        int i = it * NT + threadIdx.x;
        int c = i >> 11;
        float v = src[i];
        float y = fmaf(v - (c ? mean1 : mean0), (c ? inv1 : inv0), (c ? bet1 : bet0));
        z[i] = y / (1.f + fabsf(y));
    }
    __syncthreads();
    const float4* z4 = (const float4*)z;
    const float4* w4 = (const float4*)(Wc + (size_t)n * (HIDn * Fn));
    float acc = 0.f;
    #pragma unroll
    for (int it = 0; it < (HIDn * Fn) / (4 * NT); ++it) {
        int i = it * NT + threadIdx.x;
        float4 a = z4[i];
        float4 w = w4[i];
        acc = fmaf(a.x, w.x, acc);
        acc = fmaf(a.y, w.y, acc);
        acc = fmaf(a.z, w.z, acc);
        acc = fmaf(a.w, w.w, acc);
    }
    __shared__ float red[4];
    float s = wave_sum(acc);
    int wid = threadIdx.x >> 6, lane = threadIdx.x & 63;
    if (lane == 0) red[wid] = s;
    __syncthreads();
    if (threadIdx.x == 0) {
        float tot = (red[0] + red[1]) + (red[2] + red[3]);
        out[(size_t)b * NCLSn + n] = tot + bc[n];
    }
}

} // namespace

extern "C" void kernel_launch(void* const* d_in, const int* in_sizes, int n_in,
                              void* d_out, int out_size, void* d_ws, size_t ws_size,
                              hipStream_t stream) {
    const float* x        = (const float*)d_in[0];
    const float* neighbor = (const float*)d_in[1];
    const float* w1       = (const float*)d_in[2];
    const float* b1       = (const float*)d_in[3];
    const float* g1       = (const float*)d_in[4];
    const float* beta1    = (const float*)d_in[5];
    const float* w2       = (const float*)d_in[6];
    const float* b2       = (const float*)d_in[7];
    const float* g2       = (const float*)d_in[8];
    const float* beta2    = (const float*)d_in[9];
    const float* Wc       = (const float*)d_in[10];
    const float* bc       = (const float*)d_in[11];
    float* out = (float*)d_out;

    float* ws    = (float*)d_ws;
    float* ysum  = ws;                                  // B*F
    float* dpart = ysum + Bn * Fn;                      // GS*B*F
    float* part  = dpart + (size_t)GS * Bn * Fn;        // GS*B*HID*F
    float* out1  = part + (size_t)GS * Bn * HIDn * Fn;  // B*HID*F
    float* out2  = out1 + Bn * HIDn * Fn;               // B*HID*F
    double* stats = (double*)(out2 + Bn * HIDn * Fn);   // 8 doubles

    const dim3 grid_split(Fn / (NT * 4), GS, Bn);       // (2, 16, 32) = 1024 blocks

    ysum_kernel<<<(Bn * Fn / 4) / NT, NT, 0, stream>>>(neighbor, ysum, stats);
    denom_partial_kernel<<<grid_split, NT, 0, stream>>>(x, ysum, dpart);
    mv1_partial_kernel<<<grid_split, NT, 0, stream>>>(x, ysum, dpart, w1, b1, part);
    mv_reduce_kernel<<<(Bn * Fn / 4) / NT, NT, 0, stream>>>(part, out1, stats);
    mv2_partial_kernel<<<grid_split, NT, 0, stream>>>(x, ysum, dpart, out1, stats, g1, beta1, w2, b2, part);
    mv_reduce_kernel<<<(Bn * Fn / 4) / NT, NT, 0, stream>>>(part, out2, stats + 4);
    classifier_kernel<<<dim3(NCLSn, Bn), NT, 0, stream>>>(out2, stats + 4, g2, beta2, Wc, bc, out);
}